// Round 1
// baseline (2405.216 us; speedup 1.0000x reference)
//
#include <hip/hip_runtime.h>
#include <stdint.h>

#define DIMK 1024
#define HID  2816
#define BM   128
#define BN   128
#define BK   64

typedef __attribute__((ext_vector_type(8))) __bf16 bf16x8;
typedef __attribute__((ext_vector_type(4))) float  f32x4;

typedef const __attribute__((address_space(1))) void* gas1_t;
typedef __attribute__((address_space(3))) void*       las3_t;

__device__ __forceinline__ uint16_t f2bf(float f) {
  uint32_t u = __float_as_uint(f);
  u += 0x7FFFu + ((u >> 16) & 1u);   // round-to-nearest-even
  return (uint16_t)(u >> 16);
}

__device__ __forceinline__ void gload16(const uint16_t* g, uint16_t* l) {
  __builtin_amdgcn_global_load_lds((gas1_t)g, (las3_t)l, 16, 0, 0);
}

// stage a 128x64 bf16 tile, row-major [128][64], linear in LDS (global_load_lds needs linear dest)
__device__ __forceinline__ void stage_tile(const uint16_t* g, long rowStride, uint16_t* l, int tid) {
  const int wv = tid >> 6, lane = tid & 63;
  const int r  = lane >> 3;          // 0..7 row within 8-row segment
  const int cb = (lane & 7) * 8;     // bf16 col offset
#pragma unroll
  for (int i = 0; i < 4; ++i) {
    const int seg = wv * 4 + i;      // 0..15, 8 rows each
    gload16(g + (long)(seg * 8 + r) * rowStride + cb, l + seg * 512 + lane * 8);
  }
}

__global__ void zero_kernel(int* c) {
  if (threadIdx.x < 4) c[threadIdx.x] = 0;
}

__global__ void count_kernel(const int* __restrict__ mids, int* __restrict__ counters, int T) {
  int i = blockIdx.x * blockDim.x + threadIdx.x;
  if (i < T) atomicAdd(&counters[mids[i]], 1);
}

__global__ void convert_kernel(const float* __restrict__ src, uint16_t* __restrict__ dst, long n) {
  long i = ((long)blockIdx.x * blockDim.x + threadIdx.x) * 4;
  if (i >= n) return;
  float4 v = *(const float4*)(src + i);
  ushort4 o;
  o.x = f2bf(v.x); o.y = f2bf(v.y); o.z = f2bf(v.z); o.w = f2bf(v.w);
  *(ushort4*)(dst + i) = o;
}

// one wave per token: assign slot + gather x row to bf16
__global__ void gather_kernel(const float* __restrict__ x, const int* __restrict__ mids,
                              int* __restrict__ counters, int* __restrict__ tok,
                              uint16_t* __restrict__ xg, int T) {
  const int token = blockIdx.x * 4 + (threadIdx.x >> 6);
  if (token >= T) return;
  const int lane = threadIdx.x & 63;
  const int m = mids[token];
  int slot = 0;
  if (lane == 0) {
    int pos = atomicAdd(&counters[2 + m], 1);
    int al0 = ((counters[0] + 127) >> 7) << 7;   // modality-1 region starts tile-aligned
    slot = (m ? al0 : 0) + pos;
    tok[slot] = token;
  }
  slot = __shfl(slot, 0, 64);
  const float4* src = (const float4*)(x + (long)token * DIMK);
  uint16_t* dst = xg + (long)slot * DIMK;
#pragma unroll
  for (int j = 0; j < 4; ++j) {
    float4 v = src[lane + 64 * j];
    ushort4 o;
    o.x = f2bf(v.x); o.y = f2bf(v.y); o.z = f2bf(v.z); o.w = f2bf(v.w);
    *(ushort4*)(dst + (lane + 64 * j) * 4) = o;
  }
}

// GEMM1: [rows x 1024] x {W1,W3}[m]^T -> h = silu(x1)*x3  [rows x 2816] bf16
__global__ __launch_bounds__(256, 2) void gemm1_kernel(
    const uint16_t* __restrict__ xg, const uint16_t* __restrict__ w1b,
    const uint16_t* __restrict__ w3b, uint16_t* __restrict__ hbuf,
    const int* __restrict__ counters) {
  __shared__ __align__(16) uint16_t lsA[BM * BK];
  __shared__ __align__(16) uint16_t lsB1[BM * BK];
  __shared__ __align__(16) uint16_t lsB3[BM * BK];

  const int c0 = counters[0], c1 = counters[1];
  const int t0 = (c0 + 127) >> 7, t1 = (c1 + 127) >> 7;
  const int rt = blockIdx.x;
  if (rt >= t0 + t1) return;
  const int mod  = (rt < t0) ? 0 : 1;
  const int row0 = rt * BM;
  const int ht   = blockIdx.y;

  const int tid = threadIdx.x;
  const int lane = tid & 63, wv = tid >> 6;
  const int wr = wv >> 1, wc = wv & 1;
  const int lrow = lane & 15, lk = (lane >> 4) * 8;

  const uint16_t* gA  = xg  + (long)row0 * DIMK;
  const uint16_t* gB1 = w1b + ((long)mod * HID + ht * BN) * DIMK;
  const uint16_t* gB3 = w3b + ((long)mod * HID + ht * BN) * DIMK;

  f32x4 accG[4][4], accU[4][4];
#pragma unroll
  for (int m = 0; m < 4; ++m)
#pragma unroll
    for (int n = 0; n < 4; ++n) {
      accG[m][n] = {0.f, 0.f, 0.f, 0.f};
      accU[m][n] = {0.f, 0.f, 0.f, 0.f};
    }

  for (int kt = 0; kt < DIMK / BK; ++kt) {
    stage_tile(gA  + kt * BK, DIMK, lsA,  tid);
    stage_tile(gB1 + kt * BK, DIMK, lsB1, tid);
    stage_tile(gB3 + kt * BK, DIMK, lsB3, tid);
    asm volatile("s_waitcnt vmcnt(0)" ::: "memory");
    __syncthreads();
#pragma unroll
    for (int ks = 0; ks < 2; ++ks) {
      bf16x8 a[4], b1[4], b3[4];
#pragma unroll
      for (int m = 0; m < 4; ++m)
        a[m] = *reinterpret_cast<const bf16x8*>(&lsA[(wr * 64 + m * 16 + lrow) * BK + ks * 32 + lk]);
#pragma unroll
      for (int n = 0; n < 4; ++n) {
        b1[n] = *reinterpret_cast<const bf16x8*>(&lsB1[(wc * 64 + n * 16 + lrow) * BK + ks * 32 + lk]);
        b3[n] = *reinterpret_cast<const bf16x8*>(&lsB3[(wc * 64 + n * 16 + lrow) * BK + ks * 32 + lk]);
      }
#pragma unroll
      for (int m = 0; m < 4; ++m)
#pragma unroll
        for (int n = 0; n < 4; ++n) {
          accG[m][n] = __builtin_amdgcn_mfma_f32_16x16x32_bf16(a[m], b1[n], accG[m][n], 0, 0, 0);
          accU[m][n] = __builtin_amdgcn_mfma_f32_16x16x32_bf16(a[m], b3[n], accU[m][n], 0, 0, 0);
        }
    }
    __syncthreads();
  }

  // epilogue: h = silu(x1) * x3 -> bf16 (unconditional: gap rows harmless, keeps hbuf deterministic)
#pragma unroll
  for (int m = 0; m < 4; ++m)
#pragma unroll
    for (int n = 0; n < 4; ++n) {
      const int col = ht * BN + wc * 64 + n * 16 + lrow;
#pragma unroll
      for (int i = 0; i < 4; ++i) {
        const int row = row0 + wr * 64 + m * 16 + (lane >> 4) * 4 + i;
        float g = accG[m][n][i];
        float u = accU[m][n][i];
        float hv = (g / (1.f + __expf(-g))) * u;
        hbuf[(long)row * HID + col] = f2bf(hv);
      }
    }
}

// GEMM2: h [rows x 2816] x W2[m]^T -> scatter to out[token][0:1024]
__global__ __launch_bounds__(256, 2) void gemm2_kernel(
    const uint16_t* __restrict__ hbuf, const uint16_t* __restrict__ w2b,
    const int* __restrict__ counters, const int* __restrict__ tok,
    float* __restrict__ out) {
  __shared__ __align__(16) uint16_t lsA[BM * BK];
  __shared__ __align__(16) uint16_t lsB[BM * BK];

  const int c0 = counters[0], c1 = counters[1];
  const int t0 = (c0 + 127) >> 7, t1 = (c1 + 127) >> 7;
  const int rt = blockIdx.x;
  if (rt >= t0 + t1) return;
  const int mod  = (rt < t0) ? 0 : 1;
  const int row0 = rt * BM;
  const int ct   = blockIdx.y;
  const int vlimit = (mod == 0) ? c0 : t0 * BM + c1;

  const int tid = threadIdx.x;
  const int lane = tid & 63, wv = tid >> 6;
  const int wr = wv >> 1, wc = wv & 1;
  const int lrow = lane & 15, lk = (lane >> 4) * 8;

  const uint16_t* gA = hbuf + (long)row0 * HID;
  const uint16_t* gB = w2b + ((long)mod * DIMK + ct * BN) * HID;

  f32x4 acc[4][4];
#pragma unroll
  for (int m = 0; m < 4; ++m)
#pragma unroll
    for (int n = 0; n < 4; ++n) acc[m][n] = {0.f, 0.f, 0.f, 0.f};

  for (int kt = 0; kt < HID / BK; ++kt) {
    stage_tile(gA + kt * BK, HID, lsA, tid);
    stage_tile(gB + kt * BK, HID, lsB, tid);
    asm volatile("s_waitcnt vmcnt(0)" ::: "memory");
    __syncthreads();
#pragma unroll
    for (int ks = 0; ks < 2; ++ks) {
      bf16x8 a[4], b[4];
#pragma unroll
      for (int m = 0; m < 4; ++m)
        a[m] = *reinterpret_cast<const bf16x8*>(&lsA[(wr * 64 + m * 16 + lrow) * BK + ks * 32 + lk]);
#pragma unroll
      for (int n = 0; n < 4; ++n)
        b[n] = *reinterpret_cast<const bf16x8*>(&lsB[(wc * 64 + n * 16 + lrow) * BK + ks * 32 + lk]);
#pragma unroll
      for (int m = 0; m < 4; ++m)
#pragma unroll
        for (int n = 0; n < 4; ++n)
          acc[m][n] = __builtin_amdgcn_mfma_f32_16x16x32_bf16(a[m], b[n], acc[m][n], 0, 0, 0);
    }
    __syncthreads();
  }

#pragma unroll
  for (int m = 0; m < 4; ++m)
#pragma unroll
    for (int n = 0; n < 4; ++n) {
      const int col = ct * BN + wc * 64 + n * 16 + lrow;
#pragma unroll
      for (int i = 0; i < 4; ++i) {
        const int row = row0 + wr * 64 + m * 16 + (lane >> 4) * 4 + i;
        if (row < vlimit) {
          int t = tok[row];
          out[(long)t * DIMK + col] = acc[m][n][i];
        }
      }
    }
}

extern "C" void kernel_launch(void* const* d_in, const int* in_sizes, int n_in,
                              void* d_out, int out_size, void* d_ws, size_t ws_size,
                              hipStream_t stream) {
  const float* x   = (const float*)d_in[0];
  const int*   mids = (const int*)d_in[1];
  const float* W1  = (const float*)d_in[2];
  const float* W2  = (const float*)d_in[3];
  const float* W3  = (const float*)d_in[4];
  float* out = (float*)d_out;

  const int T   = in_sizes[1];                       // 32768 tokens
  const int CAP = ((T + 127) / 128) * 128 + 128;     // padded slot capacity (tile-aligned + gap tile)

  char* ws = (char*)d_ws;
  int* counters = (int*)ws;                          // [c0, c1, cur0, cur1]
  int* tok = (int*)(ws + 256);
  size_t off = 256 + (((size_t)CAP * 4 + 255) / 256) * 256;
  uint16_t* xg  = (uint16_t*)(ws + off); off += (size_t)CAP * DIMK * 2;
  uint16_t* w1b = (uint16_t*)(ws + off); off += (size_t)2 * HID * DIMK * 2;
  uint16_t* w3b = (uint16_t*)(ws + off); off += (size_t)2 * HID * DIMK * 2;
  uint16_t* w2b = (uint16_t*)(ws + off); off += (size_t)2 * DIMK * HID * 2;
  uint16_t* hbuf = (uint16_t*)(ws + off); off += (size_t)CAP * HID * 2;
  (void)ws_size; (void)n_in; (void)out_size;

  zero_kernel<<<1, 64, 0, stream>>>(counters);
  count_kernel<<<(T + 255) / 256, 256, 0, stream>>>(mids, counters, T);

  const long NW = (long)2 * HID * DIMK;              // elements per weight tensor
  const int cblk = (int)((NW / 4 + 255) / 256);
  convert_kernel<<<cblk, 256, 0, stream>>>(W1, w1b, NW);
  convert_kernel<<<cblk, 256, 0, stream>>>(W3, w3b, NW);
  convert_kernel<<<cblk, 256, 0, stream>>>(W2, w2b, NW);

  gather_kernel<<<(T + 3) / 4, 256, 0, stream>>>(x, mids, counters, tok, xg, T);

  const int rtiles = CAP / BM;                       // 257
  gemm1_kernel<<<dim3(rtiles, HID / BN), 256, 0, stream>>>(xg, w1b, w3b, hbuf, counters);
  gemm2_kernel<<<dim3(rtiles, DIMK / BN), 256, 0, stream>>>(hbuf, w2b, counters, tok, out);
}

// Round 2
// 790.332 us; speedup vs baseline: 3.0433x; 3.0433x over previous
//
#include <hip/hip_runtime.h>
#include <stdint.h>

#define DIMK 1024
#define HID  2816
#define BM   128
#define BN   128
#define BK   64

typedef __attribute__((ext_vector_type(8))) __bf16 bf16x8;
typedef __attribute__((ext_vector_type(4))) float  f32x4;

typedef const __attribute__((address_space(1))) void* gas1_t;
typedef __attribute__((address_space(3))) void*       las3_t;

__device__ __forceinline__ uint16_t f2bf(float f) {
  uint32_t u = __float_as_uint(f);
  u += 0x7FFFu + ((u >> 16) & 1u);   // round-to-nearest-even
  return (uint16_t)(u >> 16);
}

__device__ __forceinline__ void gload16(const uint16_t* g, uint16_t* l) {
  __builtin_amdgcn_global_load_lds((gas1_t)g, (las3_t)l, 16, 0, 0);
}

// stage a 128x64 bf16 tile, row-major [128][64], linear in LDS (global_load_lds needs linear dest)
__device__ __forceinline__ void stage_tile(const uint16_t* g, long rowStride, uint16_t* l, int tid) {
  const int wv = tid >> 6, lane = tid & 63;
  const int r  = lane >> 3;          // 0..7 row within 8-row segment
  const int cb = (lane & 7) * 8;     // bf16 col offset
#pragma unroll
  for (int i = 0; i < 4; ++i) {
    const int seg = wv * 4 + i;      // 0..15, 8 rows each
    gload16(g + (long)(seg * 8 + r) * rowStride + cb, l + seg * 512 + lane * 8);
  }
}

// ---- slot assignment: count -> scan -> rank (no contended atomics) ----

// 256 tokens per block; per-block modality histogram via ballot
__global__ void count_kernel(const int* __restrict__ mids, int* __restrict__ bc, int T) {
  const int b = blockIdx.x, t = threadIdx.x;
  const int token = b * 256 + t;
  const int lane = t & 63, wv = t >> 6;
  const int m = (token < T) ? mids[token] : -1;
  unsigned long long m0 = __ballot(m == 0);
  unsigned long long m1 = __ballot(m == 1);
  __shared__ int w0[4], w1[4];
  if (lane == 0) { w0[wv] = __popcll(m0); w1[wv] = __popcll(m1); }
  __syncthreads();
  if (t == 0) {
    bc[2 * b]     = w0[0] + w0[1] + w0[2] + w0[3];
    bc[2 * b + 1] = w1[0] + w1[1] + w1[2] + w1[3];
  }
}

// single-block exclusive scan over nb block-counts (nb <= 256)
__global__ void scan_kernel(const int* __restrict__ bc, int* __restrict__ base,
                            int* __restrict__ counters, int nb) {
  __shared__ int s0[256], s1[256];
  const int t = threadIdx.x;
  const int v0 = (t < nb) ? bc[2 * t] : 0;
  const int v1 = (t < nb) ? bc[2 * t + 1] : 0;
  s0[t] = v0; s1[t] = v1;
  __syncthreads();
  for (int off = 1; off < 256; off <<= 1) {
    int a0 = (t >= off) ? s0[t - off] : 0;
    int a1 = (t >= off) ? s1[t - off] : 0;
    __syncthreads();
    s0[t] += a0; s1[t] += a1;
    __syncthreads();
  }
  if (t < nb) { base[2 * t] = s0[t] - v0; base[2 * t + 1] = s1[t] - v1; }
  if (t == nb - 1) { counters[0] = s0[t]; counters[1] = s1[t]; }
}

// per-token slot via block base + cross-wave prefix + intra-wave ballot rank
__global__ void slot_kernel(const int* __restrict__ mids, const int* __restrict__ base,
                            const int* __restrict__ counters, int* __restrict__ tok,
                            int* __restrict__ slotof, int T) {
  const int b = blockIdx.x, t = threadIdx.x;
  const int token = b * 256 + t;
  const int lane = t & 63, wv = t >> 6;
  const int m = (token < T) ? mids[token] : -1;
  unsigned long long m0 = __ballot(m == 0);
  unsigned long long m1 = __ballot(m == 1);
  __shared__ int w0[4], w1[4];
  if (lane == 0) { w0[wv] = __popcll(m0); w1[wv] = __popcll(m1); }
  __syncthreads();
  int pre0 = 0, pre1 = 0;
  for (int w = 0; w < wv; ++w) { pre0 += w0[w]; pre1 += w1[w]; }
  if (token >= T) return;
  const unsigned long long below = (1ULL << lane) - 1ULL;
  const int c0 = counters[0];
  const int al0 = ((c0 + 127) >> 7) << 7;      // modality-1 region starts tile-aligned
  int slot;
  if (m == 0) slot = base[2 * b] + pre0 + __popcll(m0 & below);
  else        slot = al0 + base[2 * b + 1] + pre1 + __popcll(m1 & below);
  tok[slot] = token;
  slotof[token] = slot;
}

// one wave per token: streaming gather x row -> bf16 at its slot
__global__ void copy_kernel(const float* __restrict__ x, const int* __restrict__ slotof,
                            uint16_t* __restrict__ xg, int T) {
  const int token = blockIdx.x * 4 + (threadIdx.x >> 6);
  if (token >= T) return;
  const int lane = threadIdx.x & 63;
  const int slot = slotof[token];
  const float4* src = (const float4*)(x + (long)token * DIMK);
  uint16_t* dst = xg + (long)slot * DIMK;
#pragma unroll
  for (int j = 0; j < 4; ++j) {
    float4 v = src[lane + 64 * j];
    ushort4 o;
    o.x = f2bf(v.x); o.y = f2bf(v.y); o.z = f2bf(v.z); o.w = f2bf(v.w);
    *(ushort4*)(dst + (lane + 64 * j) * 4) = o;
  }
}

__global__ void convert_kernel(const float* __restrict__ src, uint16_t* __restrict__ dst, long n) {
  long i = ((long)blockIdx.x * blockDim.x + threadIdx.x) * 4;
  if (i >= n) return;
  float4 v = *(const float4*)(src + i);
  ushort4 o;
  o.x = f2bf(v.x); o.y = f2bf(v.y); o.z = f2bf(v.z); o.w = f2bf(v.w);
  *(ushort4*)(dst + i) = o;
}

// GEMM1: [rows x 1024] x {W1,W3}[m]^T -> h = silu(x1)*x3  [rows x 2816] bf16
__global__ __launch_bounds__(256, 2) void gemm1_kernel(
    const uint16_t* __restrict__ xg, const uint16_t* __restrict__ w1b,
    const uint16_t* __restrict__ w3b, uint16_t* __restrict__ hbuf,
    const int* __restrict__ counters) {
  __shared__ __align__(16) uint16_t lsA[BM * BK];
  __shared__ __align__(16) uint16_t lsB1[BM * BK];
  __shared__ __align__(16) uint16_t lsB3[BM * BK];

  const int c0 = counters[0], c1 = counters[1];
  const int t0 = (c0 + 127) >> 7, t1 = (c1 + 127) >> 7;
  const int rt = blockIdx.x;
  if (rt >= t0 + t1) return;
  const int mod  = (rt < t0) ? 0 : 1;
  const int row0 = rt * BM;
  const int ht   = blockIdx.y;

  const int tid = threadIdx.x;
  const int lane = tid & 63, wv = tid >> 6;
  const int wr = wv >> 1, wc = wv & 1;
  const int lrow = lane & 15, lk = (lane >> 4) * 8;

  const uint16_t* gA  = xg  + (long)row0 * DIMK;
  const uint16_t* gB1 = w1b + ((long)mod * HID + ht * BN) * DIMK;
  const uint16_t* gB3 = w3b + ((long)mod * HID + ht * BN) * DIMK;

  f32x4 accG[4][4], accU[4][4];
#pragma unroll
  for (int m = 0; m < 4; ++m)
#pragma unroll
    for (int n = 0; n < 4; ++n) {
      accG[m][n] = {0.f, 0.f, 0.f, 0.f};
      accU[m][n] = {0.f, 0.f, 0.f, 0.f};
    }

  for (int kt = 0; kt < DIMK / BK; ++kt) {
    stage_tile(gA  + kt * BK, DIMK, lsA,  tid);
    stage_tile(gB1 + kt * BK, DIMK, lsB1, tid);
    stage_tile(gB3 + kt * BK, DIMK, lsB3, tid);
    asm volatile("s_waitcnt vmcnt(0)" ::: "memory");
    __syncthreads();
#pragma unroll
    for (int ks = 0; ks < 2; ++ks) {
      bf16x8 a[4], b1[4], b3[4];
#pragma unroll
      for (int m = 0; m < 4; ++m)
        a[m] = *reinterpret_cast<const bf16x8*>(&lsA[(wr * 64 + m * 16 + lrow) * BK + ks * 32 + lk]);
#pragma unroll
      for (int n = 0; n < 4; ++n) {
        b1[n] = *reinterpret_cast<const bf16x8*>(&lsB1[(wc * 64 + n * 16 + lrow) * BK + ks * 32 + lk]);
        b3[n] = *reinterpret_cast<const bf16x8*>(&lsB3[(wc * 64 + n * 16 + lrow) * BK + ks * 32 + lk]);
      }
#pragma unroll
      for (int m = 0; m < 4; ++m)
#pragma unroll
        for (int n = 0; n < 4; ++n) {
          accG[m][n] = __builtin_amdgcn_mfma_f32_16x16x32_bf16(a[m], b1[n], accG[m][n], 0, 0, 0);
          accU[m][n] = __builtin_amdgcn_mfma_f32_16x16x32_bf16(a[m], b3[n], accU[m][n], 0, 0, 0);
        }
    }
    __syncthreads();
  }

  // epilogue: h = silu(x1) * x3 -> bf16 (unconditional: gap rows harmless, keeps hbuf deterministic)
#pragma unroll
  for (int m = 0; m < 4; ++m)
#pragma unroll
    for (int n = 0; n < 4; ++n) {
      const int col = ht * BN + wc * 64 + n * 16 + lrow;
#pragma unroll
      for (int i = 0; i < 4; ++i) {
        const int row = row0 + wr * 64 + m * 16 + (lane >> 4) * 4 + i;
        float g = accG[m][n][i];
        float u = accU[m][n][i];
        float hv = (g / (1.f + __expf(-g))) * u;
        hbuf[(long)row * HID + col] = f2bf(hv);
      }
    }
}

// GEMM2: h [rows x 2816] x W2[m]^T -> scatter to out[token][0:1024]
__global__ __launch_bounds__(256, 2) void gemm2_kernel(
    const uint16_t* __restrict__ hbuf, const uint16_t* __restrict__ w2b,
    const int* __restrict__ counters, const int* __restrict__ tok,
    float* __restrict__ out) {
  __shared__ __align__(16) uint16_t lsA[BM * BK];
  __shared__ __align__(16) uint16_t lsB[BM * BK];

  const int c0 = counters[0], c1 = counters[1];
  const int t0 = (c0 + 127) >> 7, t1 = (c1 + 127) >> 7;
  const int rt = blockIdx.x;
  if (rt >= t0 + t1) return;
  const int mod  = (rt < t0) ? 0 : 1;
  const int row0 = rt * BM;
  const int ct   = blockIdx.y;
  const int vlimit = (mod == 0) ? c0 : t0 * BM + c1;

  const int tid = threadIdx.x;
  const int lane = tid & 63, wv = tid >> 6;
  const int wr = wv >> 1, wc = wv & 1;
  const int lrow = lane & 15, lk = (lane >> 4) * 8;

  const uint16_t* gA = hbuf + (long)row0 * HID;
  const uint16_t* gB = w2b + ((long)mod * DIMK + ct * BN) * HID;

  f32x4 acc[4][4];
#pragma unroll
  for (int m = 0; m < 4; ++m)
#pragma unroll
    for (int n = 0; n < 4; ++n) acc[m][n] = {0.f, 0.f, 0.f, 0.f};

  for (int kt = 0; kt < HID / BK; ++kt) {
    stage_tile(gA + kt * BK, HID, lsA, tid);
    stage_tile(gB + kt * BK, HID, lsB, tid);
    asm volatile("s_waitcnt vmcnt(0)" ::: "memory");
    __syncthreads();
#pragma unroll
    for (int ks = 0; ks < 2; ++ks) {
      bf16x8 a[4], b[4];
#pragma unroll
      for (int m = 0; m < 4; ++m)
        a[m] = *reinterpret_cast<const bf16x8*>(&lsA[(wr * 64 + m * 16 + lrow) * BK + ks * 32 + lk]);
#pragma unroll
      for (int n = 0; n < 4; ++n)
        b[n] = *reinterpret_cast<const bf16x8*>(&lsB[(wc * 64 + n * 16 + lrow) * BK + ks * 32 + lk]);
#pragma unroll
      for (int m = 0; m < 4; ++m)
#pragma unroll
        for (int n = 0; n < 4; ++n)
          acc[m][n] = __builtin_amdgcn_mfma_f32_16x16x32_bf16(a[m], b[n], acc[m][n], 0, 0, 0);
    }
    __syncthreads();
  }

#pragma unroll
  for (int m = 0; m < 4; ++m)
#pragma unroll
    for (int n = 0; n < 4; ++n) {
      const int col = ct * BN + wc * 64 + n * 16 + lrow;
#pragma unroll
      for (int i = 0; i < 4; ++i) {
        const int row = row0 + wr * 64 + m * 16 + (lane >> 4) * 4 + i;
        if (row < vlimit) {
          int t = tok[row];
          out[(long)t * DIMK + col] = acc[m][n][i];
        }
      }
    }
}

extern "C" void kernel_launch(void* const* d_in, const int* in_sizes, int n_in,
                              void* d_out, int out_size, void* d_ws, size_t ws_size,
                              hipStream_t stream) {
  const float* x    = (const float*)d_in[0];
  const int*   mids = (const int*)d_in[1];
  const float* W1   = (const float*)d_in[2];
  const float* W2   = (const float*)d_in[3];
  const float* W3   = (const float*)d_in[4];
  float* out = (float*)d_out;

  const int T   = in_sizes[1];                       // 32768 tokens
  const int NB  = (T + 255) / 256;                   // 128 count blocks
  const int CAP = ((T + 127) / 128) * 128 + 128;     // padded slot capacity (tile-aligned + gap tile)

  char* ws = (char*)d_ws;
  int* counters = (int*)ws;                          // [c0, c1]
  int* bc   = (int*)(ws + 256);                      // per-block counts [NB][2]
  int* base = (int*)(ws + 256 + 2048);               // per-block bases  [NB][2]
  int* tok  = (int*)(ws + 256 + 4096);               // slot -> token
  int* slotof = tok + ((CAP + 63) & ~63);            // token -> slot
  size_t off = 256 + 4096 + (size_t)((CAP + 63) & ~63) * 4 + (size_t)((T + 63) & ~63) * 4;
  off = (off + 255) & ~(size_t)255;
  uint16_t* xg  = (uint16_t*)(ws + off); off += (size_t)CAP * DIMK * 2;
  uint16_t* w1b = (uint16_t*)(ws + off); off += (size_t)2 * HID * DIMK * 2;
  uint16_t* w3b = (uint16_t*)(ws + off); off += (size_t)2 * HID * DIMK * 2;
  uint16_t* w2b = (uint16_t*)(ws + off); off += (size_t)2 * DIMK * HID * 2;
  uint16_t* hbuf = (uint16_t*)(ws + off); off += (size_t)CAP * HID * 2;
  (void)ws_size; (void)n_in; (void)out_size;

  count_kernel<<<NB, 256, 0, stream>>>(mids, bc, T);
  scan_kernel<<<1, 256, 0, stream>>>(bc, base, counters, NB);
  slot_kernel<<<NB, 256, 0, stream>>>(mids, base, counters, tok, slotof, T);
  copy_kernel<<<(T + 3) / 4, 256, 0, stream>>>(x, slotof, xg, T);

  const long NW = (long)2 * HID * DIMK;              // elements per weight tensor
  const int cblk = (int)((NW / 4 + 255) / 256);
  convert_kernel<<<cblk, 256, 0, stream>>>(W1, w1b, NW);
  convert_kernel<<<cblk, 256, 0, stream>>>(W3, w3b, NW);
  convert_kernel<<<cblk, 256, 0, stream>>>(W2, w2b, NW);

  const int rtiles = CAP / BM;                       // 257
  gemm1_kernel<<<dim3(rtiles, HID / BN), 256, 0, stream>>>(xg, w1b, w3b, hbuf, counters);
  gemm2_kernel<<<dim3(rtiles, DIMK / BN), 256, 0, stream>>>(hbuf, w2b, counters, tok, out);
}

// Round 3
// 772.901 us; speedup vs baseline: 3.1119x; 1.0226x over previous
//
#include <hip/hip_runtime.h>
#include <stdint.h>

#define DIMK 1024
#define HID  2816

typedef __attribute__((ext_vector_type(8))) __bf16 bf16x8;
typedef __attribute__((ext_vector_type(4))) float  f32x4;

typedef const __attribute__((address_space(1))) void* gas1_t;
typedef __attribute__((address_space(3))) void*       las3_t;

__device__ __forceinline__ uint16_t f2bf(float f) {
  uint32_t u = __float_as_uint(f);
  u += 0x7FFFu + ((u >> 16) & 1u);   // round-to-nearest-even
  return (uint16_t)(u >> 16);
}

__device__ __forceinline__ void gload16(const uint16_t* g, uint16_t* l) {
  __builtin_amdgcn_global_load_lds((gas1_t)g, (las3_t)l, 16, 0, 0);
}

template<int N> __device__ __forceinline__ void wait_vm() {
  if constexpr (N == 0)      asm volatile("s_waitcnt vmcnt(0)" ::: "memory");
  else if constexpr (N == 2) asm volatile("s_waitcnt vmcnt(2)" ::: "memory");
  else                       asm volatile("s_waitcnt vmcnt(4)" ::: "memory");
}

// Stage one 128x64 bf16 half-tile (16 KB). LDS dest is LINEAR (global_load_lds
// constraint); the XOR swizzle is realized by permuting the GLOBAL source
// granule: slot (row, s) receives global granule s ^ (row&7). 2 instr/thread.
__device__ __forceinline__ void stage_half(const uint16_t* g, long stride,
                                           uint16_t* lds, int wv, int lane) {
  const int rsub = lane >> 3;                 // row within 8-row block
  const int gsw  = ((lane & 7) ^ rsub) << 3;  // inverse-swizzled source granule (elems)
#pragma unroll
  for (int j = 0; j < 2; ++j) {
    const int blk = j * 8 + wv;               // 16 blocks x 8 rows = 128 rows
    gload16(g + (long)(blk * 8 + rsub) * stride + gsw,
            lds + blk * 512 + lane * 8);
  }
}

// Swizzled fragment read: logical (row r, 16B-granule g) lives at slot g^(r&7).
__device__ __forceinline__ bf16x8 ldsf(const uint16_t* lds, int r, int g) {
  return *reinterpret_cast<const bf16x8*>(lds + r * 64 + ((g ^ (r & 7)) << 3));
}

// ---- slot assignment: count -> scan -> rank (no contended atomics) ----

__global__ void count_kernel(const int* __restrict__ mids, int* __restrict__ bc, int T) {
  const int b = blockIdx.x, t = threadIdx.x;
  const int token = b * 256 + t;
  const int lane = t & 63, wv = t >> 6;
  const int m = (token < T) ? mids[token] : -1;
  unsigned long long m0 = __ballot(m == 0);
  unsigned long long m1 = __ballot(m == 1);
  __shared__ int w0[4], w1[4];
  if (lane == 0) { w0[wv] = __popcll(m0); w1[wv] = __popcll(m1); }
  __syncthreads();
  if (t == 0) {
    bc[2 * b]     = w0[0] + w0[1] + w0[2] + w0[3];
    bc[2 * b + 1] = w1[0] + w1[1] + w1[2] + w1[3];
  }
}

__global__ void scan_kernel(const int* __restrict__ bc, int* __restrict__ base,
                            int* __restrict__ counters, int nb) {
  __shared__ int s0[256], s1[256];
  const int t = threadIdx.x;
  const int v0 = (t < nb) ? bc[2 * t] : 0;
  const int v1 = (t < nb) ? bc[2 * t + 1] : 0;
  s0[t] = v0; s1[t] = v1;
  __syncthreads();
  for (int off = 1; off < 256; off <<= 1) {
    int a0 = (t >= off) ? s0[t - off] : 0;
    int a1 = (t >= off) ? s1[t - off] : 0;
    __syncthreads();
    s0[t] += a0; s1[t] += a1;
    __syncthreads();
  }
  if (t < nb) { base[2 * t] = s0[t] - v0; base[2 * t + 1] = s1[t] - v1; }
  if (t == nb - 1) { counters[0] = s0[t]; counters[1] = s1[t]; }
}

__global__ void slot_kernel(const int* __restrict__ mids, const int* __restrict__ base,
                            const int* __restrict__ counters, int* __restrict__ tok,
                            int* __restrict__ slotof, int T) {
  const int b = blockIdx.x, t = threadIdx.x;
  const int token = b * 256 + t;
  const int lane = t & 63, wv = t >> 6;
  const int m = (token < T) ? mids[token] : -1;
  unsigned long long m0 = __ballot(m == 0);
  unsigned long long m1 = __ballot(m == 1);
  __shared__ int w0[4], w1[4];
  if (lane == 0) { w0[wv] = __popcll(m0); w1[wv] = __popcll(m1); }
  __syncthreads();
  int pre0 = 0, pre1 = 0;
  for (int w = 0; w < wv; ++w) { pre0 += w0[w]; pre1 += w1[w]; }
  if (token >= T) return;
  const unsigned long long below = (1ULL << lane) - 1ULL;
  const int c0 = counters[0];
  const int al0 = ((c0 + 255) >> 8) << 8;      // modality-1 region starts 256-tile-aligned
  int slot;
  if (m == 0) slot = base[2 * b] + pre0 + __popcll(m0 & below);
  else        slot = al0 + base[2 * b + 1] + pre1 + __popcll(m1 & below);
  tok[slot] = token;
  slotof[token] = slot;
}

__global__ void copy_kernel(const float* __restrict__ x, const int* __restrict__ slotof,
                            uint16_t* __restrict__ xg, int T) {
  const int token = blockIdx.x * 4 + (threadIdx.x >> 6);
  if (token >= T) return;
  const int lane = threadIdx.x & 63;
  const int slot = slotof[token];
  const float4* src = (const float4*)(x + (long)token * DIMK);
  uint16_t* dst = xg + (long)slot * DIMK;
#pragma unroll
  for (int j = 0; j < 4; ++j) {
    float4 v = src[lane + 64 * j];
    ushort4 o;
    o.x = f2bf(v.x); o.y = f2bf(v.y); o.z = f2bf(v.z); o.w = f2bf(v.w);
    *(ushort4*)(dst + (lane + 64 * j) * 4) = o;
  }
}

__global__ void convert_kernel(const float* __restrict__ src, uint16_t* __restrict__ dst, long n) {
  long i = ((long)blockIdx.x * blockDim.x + threadIdx.x) * 4;
  if (i >= n) return;
  float4 v = *(const float4*)(src + i);
  ushort4 o;
  o.x = f2bf(v.x); o.y = f2bf(v.y); o.z = f2bf(v.z); o.w = f2bf(v.w);
  *(ushort4*)(dst + i) = o;
}

// ---------------- GEMM1: 256x128 tile, dual-B (W1,W3), 4 phases/K-tile ----------------
// Stage-unit issue order per K-tile: [A0, B1, B3, A1]; phase needs: {A0,B1},{B3},{A1},{}.
// Counted waits: main loop (4,4,4,-), last tile (4,2,0,-). Never vmcnt(0) in main loop.

template<bool PF, int W0, int W1, int W2>
__device__ __forceinline__ void g1_tile(
    const uint16_t* Ac, const uint16_t* B1c, const uint16_t* B3c,
    uint16_t* An, uint16_t* B1n, uint16_t* B3n,
    const uint16_t* gA, const uint16_t* gB1, const uint16_t* gB3, long ko,
    int wv, int lane, int wr, int wc, int lrow, int grp,
    f32x4 (&accG)[8][2], f32x4 (&accU)[8][2]) {
  bf16x8 a[4][2], b1[2][2], b3[2][2];
  // ---- ph0: load A0+B1 frags, stage A0(t+1), MFMA G[m0..3]
  wait_vm<W0>();
  __builtin_amdgcn_s_barrier();
  asm volatile("" ::: "memory");
#pragma unroll
  for (int m = 0; m < 4; ++m)
#pragma unroll
    for (int ks = 0; ks < 2; ++ks)
      a[m][ks] = ldsf(Ac, m * 32 + wr * 16 + lrow, ks * 4 + grp);
#pragma unroll
  for (int n = 0; n < 2; ++n)
#pragma unroll
    for (int ks = 0; ks < 2; ++ks)
      b1[n][ks] = ldsf(B1c, wc * 32 + n * 16 + lrow, ks * 4 + grp);
  if constexpr (PF) stage_half(gA + ko, DIMK, An, wv, lane);
  asm volatile("s_waitcnt lgkmcnt(0)" ::: "memory");
  __builtin_amdgcn_sched_barrier(0);
  __builtin_amdgcn_s_setprio(1);
#pragma unroll
  for (int ks = 0; ks < 2; ++ks)
#pragma unroll
    for (int m = 0; m < 4; ++m)
#pragma unroll
      for (int n = 0; n < 2; ++n)
        accG[m][n] = __builtin_amdgcn_mfma_f32_16x16x32_bf16(a[m][ks], b1[n][ks], accG[m][n], 0, 0, 0);
  __builtin_amdgcn_s_setprio(0);
  // ---- ph1: load B3 frags, stage B1(t+1), MFMA U[m0..3]
  wait_vm<W1>();
  __builtin_amdgcn_s_barrier();
  asm volatile("" ::: "memory");
#pragma unroll
  for (int n = 0; n < 2; ++n)
#pragma unroll
    for (int ks = 0; ks < 2; ++ks)
      b3[n][ks] = ldsf(B3c, wc * 32 + n * 16 + lrow, ks * 4 + grp);
  if constexpr (PF) stage_half(gB1 + ko, DIMK, B1n, wv, lane);
  asm volatile("s_waitcnt lgkmcnt(0)" ::: "memory");
  __builtin_amdgcn_sched_barrier(0);
  __builtin_amdgcn_s_setprio(1);
#pragma unroll
  for (int ks = 0; ks < 2; ++ks)
#pragma unroll
    for (int m = 0; m < 4; ++m)
#pragma unroll
      for (int n = 0; n < 2; ++n)
        accU[m][n] = __builtin_amdgcn_mfma_f32_16x16x32_bf16(a[m][ks], b3[n][ks], accU[m][n], 0, 0, 0);
  __builtin_amdgcn_s_setprio(0);
  // ---- ph2: load A1 frags, stage B3(t+1), MFMA G[m4..7]
  wait_vm<W2>();
  __builtin_amdgcn_s_barrier();
  asm volatile("" ::: "memory");
#pragma unroll
  for (int m = 0; m < 4; ++m)
#pragma unroll
    for (int ks = 0; ks < 2; ++ks)
      a[m][ks] = ldsf(Ac, (m + 4) * 32 + wr * 16 + lrow, ks * 4 + grp);
  if constexpr (PF) stage_half(gB3 + ko, DIMK, B3n, wv, lane);
  asm volatile("s_waitcnt lgkmcnt(0)" ::: "memory");
  __builtin_amdgcn_sched_barrier(0);
  __builtin_amdgcn_s_setprio(1);
#pragma unroll
  for (int ks = 0; ks < 2; ++ks)
#pragma unroll
    for (int m = 0; m < 4; ++m)
#pragma unroll
      for (int n = 0; n < 2; ++n)
        accG[m + 4][n] = __builtin_amdgcn_mfma_f32_16x16x32_bf16(a[m][ks], b1[n][ks], accG[m + 4][n], 0, 0, 0);
  __builtin_amdgcn_s_setprio(0);
  // ---- ph3: stage A1(t+1), MFMA U[m4..7] (no wait/barrier: all operands in regs)
  if constexpr (PF) stage_half(gA + 128 * DIMK + ko, DIMK, An + 128 * 64, wv, lane);
  __builtin_amdgcn_s_setprio(1);
#pragma unroll
  for (int ks = 0; ks < 2; ++ks)
#pragma unroll
    for (int m = 0; m < 4; ++m)
#pragma unroll
      for (int n = 0; n < 2; ++n)
        accU[m + 4][n] = __builtin_amdgcn_mfma_f32_16x16x32_bf16(a[m][ks], b3[n][ks], accU[m + 4][n], 0, 0, 0);
  __builtin_amdgcn_s_setprio(0);
}

__global__ __launch_bounds__(512, 2) void gemm1_kernel(
    const uint16_t* __restrict__ xg, const uint16_t* __restrict__ w1b,
    const uint16_t* __restrict__ w3b, uint16_t* __restrict__ hbuf,
    const int* __restrict__ counters) {
  __shared__ __align__(16) uint16_t lsA[2][256 * 64];    // 64 KB
  __shared__ __align__(16) uint16_t lsB1[2][128 * 64];   // 32 KB
  __shared__ __align__(16) uint16_t lsB3[2][128 * 64];   // 32 KB

  const int c0 = counters[0], c1 = counters[1];
  const int t0 = (c0 + 255) >> 8, t1 = (c1 + 255) >> 8;
  // bijective XCD swizzle (m204): each XCD gets a contiguous chunk of the
  // ht-major order -> same-XCD blocks share the B-panel in its L2.
  const int GX = gridDim.x;
  const int nwg = GX * (int)gridDim.y;
  const int orig = blockIdx.y * GX + blockIdx.x;
  const int q = nwg >> 3, r = nwg & 7;
  const int xcd = orig & 7, loc = orig >> 3;
  const int swz = (xcd < r ? xcd * (q + 1) : r * (q + 1) + (xcd - r) * q) + loc;
  const int ht = swz / GX;
  const int rt = swz - ht * GX;
  if (rt >= t0 + t1) return;
  const int mod = (rt < t0) ? 0 : 1;
  const long row0 = (long)rt * 256;

  const int tid = threadIdx.x, lane = tid & 63, wv = tid >> 6;
  const int wr = wv >> 2, wc = wv & 3;            // 2M x 4N waves
  const int lrow = lane & 15, grp = lane >> 4;

  const uint16_t* gA  = xg  + row0 * DIMK;
  const uint16_t* gB1 = w1b + ((long)mod * HID + ht * 128) * DIMK;
  const uint16_t* gB3 = w3b + ((long)mod * HID + ht * 128) * DIMK;

  f32x4 accG[8][2], accU[8][2];
#pragma unroll
  for (int m = 0; m < 8; ++m)
#pragma unroll
    for (int n = 0; n < 2; ++n) {
      accG[m][n] = {0.f, 0.f, 0.f, 0.f};
      accU[m][n] = {0.f, 0.f, 0.f, 0.f};
    }

  // prologue: tile 0 -> buf 0, in issue order [A0, B1, B3, A1]; no drain.
  stage_half(gA,             DIMK, &lsA[0][0],        wv, lane);
  stage_half(gB1,            DIMK, &lsB1[0][0],       wv, lane);
  stage_half(gB3,            DIMK, &lsB3[0][0],       wv, lane);
  stage_half(gA + 128 * DIMK, DIMK, &lsA[0][128 * 64], wv, lane);

  const int NT = DIMK / 64;                        // 16
  int cur = 0;
  for (int t = 0; t < NT - 1; ++t) {
    g1_tile<true, 4, 4, 4>(&lsA[cur][0], &lsB1[cur][0], &lsB3[cur][0],
                           &lsA[cur ^ 1][0], &lsB1[cur ^ 1][0], &lsB3[cur ^ 1][0],
                           gA, gB1, gB3, (long)(t + 1) * 64,
                           wv, lane, wr, wc, lrow, grp, accG, accU);
    cur ^= 1;
  }
  g1_tile<false, 4, 2, 0>(&lsA[cur][0], &lsB1[cur][0], &lsB3[cur][0],
                          &lsA[cur ^ 1][0], &lsB1[cur ^ 1][0], &lsB3[cur ^ 1][0],
                          gA, gB1, gB3, 0,
                          wv, lane, wr, wc, lrow, grp, accG, accU);

  // epilogue: h = silu(x1) * x3 -> bf16 (gap rows harmless, never scattered)
#pragma unroll
  for (int m = 0; m < 8; ++m)
#pragma unroll
    for (int n = 0; n < 2; ++n) {
      const int col = ht * 128 + wc * 32 + n * 16 + lrow;
#pragma unroll
      for (int i = 0; i < 4; ++i) {
        const long row = row0 + m * 32 + wr * 16 + grp * 4 + i;
        float g = accG[m][n][i];
        float u = accU[m][n][i];
        float hv = (g / (1.f + __expf(-g))) * u;
        hbuf[row * HID + col] = f2bf(hv);
      }
    }
}

// ---------------- GEMM2: 256x128 tile, 2 phases/K-tile ----------------
// Stage-unit issue order per K-tile: [A0, B, A1]; phase needs: {A0,B},{A1}.
// Counted waits: main loop (2,4), last tile (2,0).

template<bool PF, int W0, int W1>
__device__ __forceinline__ void g2_tile(
    const uint16_t* Ac, const uint16_t* Bc, uint16_t* An, uint16_t* Bn,
    const uint16_t* gA, const uint16_t* gB, long ko,
    int wv, int lane, int wr, int wc, int lrow, int grp,
    f32x4 (&acc)[8][2]) {
  bf16x8 a[4][2], b[2][2];
  // ---- ph0
  wait_vm<W0>();
  __builtin_amdgcn_s_barrier();
  asm volatile("" ::: "memory");
#pragma unroll
  for (int m = 0; m < 4; ++m)
#pragma unroll
    for (int ks = 0; ks < 2; ++ks)
      a[m][ks] = ldsf(Ac, m * 32 + wr * 16 + lrow, ks * 4 + grp);
#pragma unroll
  for (int n = 0; n < 2; ++n)
#pragma unroll
    for (int ks = 0; ks < 2; ++ks)
      b[n][ks] = ldsf(Bc, wc * 32 + n * 16 + lrow, ks * 4 + grp);
  if constexpr (PF) {
    stage_half(gA + ko, HID, An, wv, lane);
    stage_half(gB + ko, HID, Bn, wv, lane);
  }
  asm volatile("s_waitcnt lgkmcnt(0)" ::: "memory");
  __builtin_amdgcn_sched_barrier(0);
  __builtin_amdgcn_s_setprio(1);
#pragma unroll
  for (int ks = 0; ks < 2; ++ks)
#pragma unroll
    for (int m = 0; m < 4; ++m)
#pragma unroll
      for (int n = 0; n < 2; ++n)
        acc[m][n] = __builtin_amdgcn_mfma_f32_16x16x32_bf16(a[m][ks], b[n][ks], acc[m][n], 0, 0, 0);
  __builtin_amdgcn_s_setprio(0);
  // ---- ph1
  wait_vm<W1>();
  __builtin_amdgcn_s_barrier();
  asm volatile("" ::: "memory");
#pragma unroll
  for (int m = 0; m < 4; ++m)
#pragma unroll
    for (int ks = 0; ks < 2; ++ks)
      a[m][ks] = ldsf(Ac, (m + 4) * 32 + wr * 16 + lrow, ks * 4 + grp);
  if constexpr (PF) stage_half(gA + 128 * HID + ko, HID, An + 128 * 64, wv, lane);
  asm volatile("s_waitcnt lgkmcnt(0)" ::: "memory");
  __builtin_amdgcn_sched_barrier(0);
  __builtin_amdgcn_s_setprio(1);
#pragma unroll
  for (int ks = 0; ks < 2; ++ks)
#pragma unroll
    for (int m = 0; m < 4; ++m)
#pragma unroll
      for (int n = 0; n < 2; ++n)
        acc[m + 4][n] = __builtin_amdgcn_mfma_f32_16x16x32_bf16(a[m][ks], b[n][ks], acc[m + 4][n], 0, 0, 0);
  __builtin_amdgcn_s_setprio(0);
}

__global__ __launch_bounds__(512, 2) void gemm2_kernel(
    const uint16_t* __restrict__ hbuf, const uint16_t* __restrict__ w2b,
    const int* __restrict__ counters, const int* __restrict__ tok,
    float* __restrict__ out) {
  __shared__ __align__(16) uint16_t lsA[2][256 * 64];    // 64 KB
  __shared__ __align__(16) uint16_t lsB[2][128 * 64];    // 32 KB

  const int c0 = counters[0], c1 = counters[1];
  const int t0 = (c0 + 255) >> 8, t1 = (c1 + 255) >> 8;
  const int GX = gridDim.x;
  const int nwg = GX * (int)gridDim.y;
  const int orig = blockIdx.y * GX + blockIdx.x;
  const int q = nwg >> 3, r = nwg & 7;
  const int xcd = orig & 7, loc = orig >> 3;
  const int swz = (xcd < r ? xcd * (q + 1) : r * (q + 1) + (xcd - r) * q) + loc;
  const int ct = swz / GX;
  const int rt = swz - ct * GX;
  if (rt >= t0 + t1) return;
  const int mod = (rt < t0) ? 0 : 1;
  const long row0 = (long)rt * 256;
  const int vlimit = (mod == 0) ? c0 : t0 * 256 + c1;

  const int tid = threadIdx.x, lane = tid & 63, wv = tid >> 6;
  const int wr = wv >> 2, wc = wv & 3;
  const int lrow = lane & 15, grp = lane >> 4;

  const uint16_t* gA = hbuf + row0 * HID;
  const uint16_t* gB = w2b + ((long)mod * DIMK + ct * 128) * HID;

  f32x4 acc[8][2];
#pragma unroll
  for (int m = 0; m < 8; ++m)
#pragma unroll
    for (int n = 0; n < 2; ++n) acc[m][n] = {0.f, 0.f, 0.f, 0.f};

  // prologue: tile 0 -> buf 0, issue order [A0, B, A1]
  stage_half(gA,             HID, &lsA[0][0],        wv, lane);
  stage_half(gB,             HID, &lsB[0][0],        wv, lane);
  stage_half(gA + 128 * HID, HID, &lsA[0][128 * 64], wv, lane);

  const int NT = HID / 64;                         // 44
  int cur = 0;
  for (int t = 0; t < NT - 1; ++t) {
    g2_tile<true, 2, 4>(&lsA[cur][0], &lsB[cur][0],
                        &lsA[cur ^ 1][0], &lsB[cur ^ 1][0],
                        gA, gB, (long)(t + 1) * 64,
                        wv, lane, wr, wc, lrow, grp, acc);
    cur ^= 1;
  }
  g2_tile<false, 2, 0>(&lsA[cur][0], &lsB[cur][0],
                       &lsA[cur ^ 1][0], &lsB[cur ^ 1][0],
                       gA, gB, 0,
                       wv, lane, wr, wc, lrow, grp, acc);

#pragma unroll
  for (int m = 0; m < 8; ++m)
#pragma unroll
    for (int n = 0; n < 2; ++n) {
      const int col = ct * 128 + wc * 32 + n * 16 + lrow;
#pragma unroll
      for (int i = 0; i < 4; ++i) {
        const int row = (int)row0 + m * 32 + wr * 16 + grp * 4 + i;
        if (row < vlimit) {
          out[(long)tok[row] * DIMK + col] = acc[m][n][i];
        }
      }
    }
}

extern "C" void kernel_launch(void* const* d_in, const int* in_sizes, int n_in,
                              void* d_out, int out_size, void* d_ws, size_t ws_size,
                              hipStream_t stream) {
  const float* x    = (const float*)d_in[0];
  const int*   mids = (const int*)d_in[1];
  const float* W1   = (const float*)d_in[2];
  const float* W2   = (const float*)d_in[3];
  const float* W3   = (const float*)d_in[4];
  float* out = (float*)d_out;

  const int T   = in_sizes[1];                       // 32768 tokens
  const int NB  = (T + 255) / 256;                   // 128 count blocks
  const int CAP = ((T + 255) & ~255) + 256;          // 256-aligned capacity + gap tile

  char* ws = (char*)d_ws;
  int* counters = (int*)ws;                          // [c0, c1]
  int* bc   = (int*)(ws + 256);                      // per-block counts [NB][2]
  int* base = (int*)(ws + 256 + 2048);               // per-block bases  [NB][2]
  int* tok  = (int*)(ws + 256 + 4096);               // slot -> token
  int* slotof = tok + ((CAP + 63) & ~63);            // token -> slot
  size_t off = 256 + 4096 + (size_t)((CAP + 63) & ~63) * 4 + (size_t)((T + 63) & ~63) * 4;
  off = (off + 255) & ~(size_t)255;
  uint16_t* xg  = (uint16_t*)(ws + off); off += (size_t)CAP * DIMK * 2;
  uint16_t* w1b = (uint16_t*)(ws + off); off += (size_t)2 * HID * DIMK * 2;
  uint16_t* w3b = (uint16_t*)(ws + off); off += (size_t)2 * HID * DIMK * 2;
  uint16_t* w2b = (uint16_t*)(ws + off); off += (size_t)2 * DIMK * HID * 2;
  uint16_t* hbuf = (uint16_t*)(ws + off); off += (size_t)CAP * HID * 2;
  (void)ws_size; (void)n_in; (void)out_size;

  count_kernel<<<NB, 256, 0, stream>>>(mids, bc, T);
  scan_kernel<<<1, 256, 0, stream>>>(bc, base, counters, NB);
  slot_kernel<<<NB, 256, 0, stream>>>(mids, base, counters, tok, slotof, T);
  copy_kernel<<<(T + 3) / 4, 256, 0, stream>>>(x, slotof, xg, T);

  const long NW = (long)2 * HID * DIMK;              // elements per weight tensor
  const int cblk = (int)((NW / 4 + 255) / 256);
  convert_kernel<<<cblk, 256, 0, stream>>>(W1, w1b, NW);
  convert_kernel<<<cblk, 256, 0, stream>>>(W3, w3b, NW);
  convert_kernel<<<cblk, 256, 0, stream>>>(W2, w2b, NW);

  const int rtiles = CAP / 256;                      // 129
  gemm1_kernel<<<dim3(rtiles, HID / 128), 512, 0, stream>>>(xg, w1b, w3b, hbuf, counters);
  gemm2_kernel<<<dim3(rtiles, DIMK / 128), 512, 0, stream>>>(hbuf, w2b, counters, tok, out);
}

// Round 4
// 767.203 us; speedup vs baseline: 3.1350x; 1.0074x over previous
//
#include <hip/hip_runtime.h>
#include <stdint.h>

#define DIMK 1024
#define HID  2816

typedef __attribute__((ext_vector_type(8))) __bf16 bf16x8;
typedef __attribute__((ext_vector_type(4))) float  f32x4;

typedef const __attribute__((address_space(1))) void* gas1_t;
typedef __attribute__((address_space(3))) void*       las3_t;

__device__ __forceinline__ uint16_t f2bf(float f) {
  uint32_t u = __float_as_uint(f);
  u += 0x7FFFu + ((u >> 16) & 1u);   // round-to-nearest-even
  return (uint16_t)(u >> 16);
}

__device__ __forceinline__ void gload16(const uint16_t* g, uint16_t* l) {
  __builtin_amdgcn_global_load_lds((gas1_t)g, (las3_t)l, 16, 0, 0);
}

template<int N> __device__ __forceinline__ void wait_vm() {
  if constexpr (N == 0)      asm volatile("s_waitcnt vmcnt(0)" ::: "memory");
  else if constexpr (N == 2) asm volatile("s_waitcnt vmcnt(2)" ::: "memory");
  else                       asm volatile("s_waitcnt vmcnt(6)" ::: "memory");
}

// Stage one 128x64 bf16 half-tile (16 KB). LDS dest is LINEAR (global_load_lds
// constraint); the XOR swizzle is realized by permuting the GLOBAL source
// granule: slot (row, s) receives global granule s ^ (row&7). 2 instr/thread.
__device__ __forceinline__ void stage_half(const uint16_t* g, long stride,
                                           uint16_t* lds, int wv, int lane) {
  const int rsub = lane >> 3;                 // row within 8-row block
  const int gsw  = ((lane & 7) ^ rsub) << 3;  // inverse-swizzled source granule (elems)
#pragma unroll
  for (int j = 0; j < 2; ++j) {
    const int blk = j * 8 + wv;               // 16 blocks x 8 rows = 128 rows
    gload16(g + (long)(blk * 8 + rsub) * stride + gsw,
            lds + blk * 512 + lane * 8);
  }
}

// Swizzled fragment read: logical (row r, 16B-granule g) lives at slot g^(r&7).
__device__ __forceinline__ bf16x8 ldsf(const uint16_t* lds, int r, int g) {
  return *reinterpret_cast<const bf16x8*>(lds + r * 64 + ((g ^ (r & 7)) << 3));
}

// ---- slot assignment: count -> scan -> rank (no contended atomics) ----

__global__ void count_kernel(const int* __restrict__ mids, int* __restrict__ bc, int T) {
  const int b = blockIdx.x, t = threadIdx.x;
  const int token = b * 256 + t;
  const int lane = t & 63, wv = t >> 6;
  const int m = (token < T) ? mids[token] : -1;
  unsigned long long m0 = __ballot(m == 0);
  unsigned long long m1 = __ballot(m == 1);
  __shared__ int w0[4], w1[4];
  if (lane == 0) { w0[wv] = __popcll(m0); w1[wv] = __popcll(m1); }
  __syncthreads();
  if (t == 0) {
    bc[2 * b]     = w0[0] + w0[1] + w0[2] + w0[3];
    bc[2 * b + 1] = w1[0] + w1[1] + w1[2] + w1[3];
  }
}

__global__ void scan_kernel(const int* __restrict__ bc, int* __restrict__ base,
                            int* __restrict__ counters, int nb) {
  __shared__ int s0[256], s1[256];
  const int t = threadIdx.x;
  const int v0 = (t < nb) ? bc[2 * t] : 0;
  const int v1 = (t < nb) ? bc[2 * t + 1] : 0;
  s0[t] = v0; s1[t] = v1;
  __syncthreads();
  for (int off = 1; off < 256; off <<= 1) {
    int a0 = (t >= off) ? s0[t - off] : 0;
    int a1 = (t >= off) ? s1[t - off] : 0;
    __syncthreads();
    s0[t] += a0; s1[t] += a1;
    __syncthreads();
  }
  if (t < nb) { base[2 * t] = s0[t] - v0; base[2 * t + 1] = s1[t] - v1; }
  if (t == nb - 1) { counters[0] = s0[t]; counters[1] = s1[t]; }
}

__global__ void slot_kernel(const int* __restrict__ mids, const int* __restrict__ base,
                            const int* __restrict__ counters, int* __restrict__ tok,
                            int* __restrict__ slotof, int T) {
  const int b = blockIdx.x, t = threadIdx.x;
  const int token = b * 256 + t;
  const int lane = t & 63, wv = t >> 6;
  const int m = (token < T) ? mids[token] : -1;
  unsigned long long m0 = __ballot(m == 0);
  unsigned long long m1 = __ballot(m == 1);
  __shared__ int w0[4], w1[4];
  if (lane == 0) { w0[wv] = __popcll(m0); w1[wv] = __popcll(m1); }
  __syncthreads();
  int pre0 = 0, pre1 = 0;
  for (int w = 0; w < wv; ++w) { pre0 += w0[w]; pre1 += w1[w]; }
  if (token >= T) return;
  const unsigned long long below = (1ULL << lane) - 1ULL;
  const int c0 = counters[0];
  const int al0 = ((c0 + 255) >> 8) << 8;      // modality-1 region starts 256-tile-aligned
  int slot;
  if (m == 0) slot = base[2 * b] + pre0 + __popcll(m0 & below);
  else        slot = al0 + base[2 * b + 1] + pre1 + __popcll(m1 & below);
  tok[slot] = token;
  slotof[token] = slot;
}

__global__ void copy_kernel(const float* __restrict__ x, const int* __restrict__ slotof,
                            uint16_t* __restrict__ xg, int T) {
  const int token = blockIdx.x * 4 + (threadIdx.x >> 6);
  if (token >= T) return;
  const int lane = threadIdx.x & 63;
  const int slot = slotof[token];
  const float4* src = (const float4*)(x + (long)token * DIMK);
  uint16_t* dst = xg + (long)slot * DIMK;
#pragma unroll
  for (int j = 0; j < 4; ++j) {
    float4 v = src[lane + 64 * j];
    ushort4 o;
    o.x = f2bf(v.x); o.y = f2bf(v.y); o.z = f2bf(v.z); o.w = f2bf(v.w);
    *(ushort4*)(dst + (lane + 64 * j) * 4) = o;
  }
}

__global__ void convert_kernel(const float* __restrict__ src, uint16_t* __restrict__ dst, long n) {
  long i = ((long)blockIdx.x * blockDim.x + threadIdx.x) * 4;
  if (i >= n) return;
  float4 v = *(const float4*)(src + i);
  ushort4 o;
  o.x = f2bf(v.x); o.y = f2bf(v.y); o.z = f2bf(v.z); o.w = f2bf(v.w);
  *(ushort4*)(dst + i) = o;
}

// ---------------- GEMM1: 256x128 tile, dual-B (W1,W3), 4 phases/K-tile ----------------
// Stage groups per K-tile: group1 = {A-low, B1, B3} (6 loads/thread),
// group2 = {A-high} (2 loads). Waits: vmcnt(2) @ph0 completes group1(t) (issued
// t-1 ph0, distance 4 phases); vmcnt(6) @ph2 completes group2(t) (t-1 ph2,
// distance 4). 2 waits + 2 barriers per K-tile; never vmcnt(0) in main loop.
// Phases: 8/8/4/4 ds_reads, 16 MFMA each.

template<bool PF, int W0, int W2>
__device__ __forceinline__ void g1_tile(
    const uint16_t* Ac, const uint16_t* B1c, const uint16_t* B3c,
    uint16_t* An, uint16_t* B1n, uint16_t* B3n,
    const uint16_t* gA, const uint16_t* gB1, const uint16_t* gB3, long ko,
    int wv, int lane, int wr, int wc, int lrow, int grp,
    f32x4 (&accG)[8][2], f32x4 (&accU)[8][2]) {
  bf16x8 a[4][2], b1[2][2], b3[2][2];
  // ---- ph0: guard group1; read ks0 of A-low/B1/B3; stage group1(t+1); MFMA low-ks0
  wait_vm<W0>();
  __builtin_amdgcn_s_barrier();
  asm volatile("" ::: "memory");
#pragma unroll
  for (int m = 0; m < 4; ++m)
    a[m][0] = ldsf(Ac, m * 32 + wr * 16 + lrow, grp);
#pragma unroll
  for (int n = 0; n < 2; ++n) {
    b1[n][0] = ldsf(B1c, wc * 32 + n * 16 + lrow, grp);
    b3[n][0] = ldsf(B3c, wc * 32 + n * 16 + lrow, grp);
  }
  if constexpr (PF) {
    stage_half(gA  + ko, DIMK, An,  wv, lane);
    stage_half(gB1 + ko, DIMK, B1n, wv, lane);
    stage_half(gB3 + ko, DIMK, B3n, wv, lane);
  }
  asm volatile("s_waitcnt lgkmcnt(0)" ::: "memory");
  __builtin_amdgcn_sched_barrier(0);
  __builtin_amdgcn_s_setprio(1);
#pragma unroll
  for (int m = 0; m < 4; ++m)
#pragma unroll
    for (int n = 0; n < 2; ++n) {
      accG[m][n] = __builtin_amdgcn_mfma_f32_16x16x32_bf16(a[m][0], b1[n][0], accG[m][n], 0, 0, 0);
      accU[m][n] = __builtin_amdgcn_mfma_f32_16x16x32_bf16(a[m][0], b3[n][0], accU[m][n], 0, 0, 0);
    }
  __builtin_amdgcn_s_setprio(0);
  // ---- ph1: read ks1 of A-low/B1/B3; MFMA low-ks1
#pragma unroll
  for (int m = 0; m < 4; ++m)
    a[m][1] = ldsf(Ac, m * 32 + wr * 16 + lrow, 4 + grp);
#pragma unroll
  for (int n = 0; n < 2; ++n) {
    b1[n][1] = ldsf(B1c, wc * 32 + n * 16 + lrow, 4 + grp);
    b3[n][1] = ldsf(B3c, wc * 32 + n * 16 + lrow, 4 + grp);
  }
  asm volatile("s_waitcnt lgkmcnt(0)" ::: "memory");
  __builtin_amdgcn_sched_barrier(0);
  __builtin_amdgcn_s_setprio(1);
#pragma unroll
  for (int m = 0; m < 4; ++m)
#pragma unroll
    for (int n = 0; n < 2; ++n) {
      accG[m][n] = __builtin_amdgcn_mfma_f32_16x16x32_bf16(a[m][1], b1[n][1], accG[m][n], 0, 0, 0);
      accU[m][n] = __builtin_amdgcn_mfma_f32_16x16x32_bf16(a[m][1], b3[n][1], accU[m][n], 0, 0, 0);
    }
  __builtin_amdgcn_s_setprio(0);
  // ---- ph2: guard group2; read A-high ks0; stage group2(t+1); MFMA high-ks0
  wait_vm<W2>();
  __builtin_amdgcn_s_barrier();
  asm volatile("" ::: "memory");
#pragma unroll
  for (int m = 0; m < 4; ++m)
    a[m][0] = ldsf(Ac, (m + 4) * 32 + wr * 16 + lrow, grp);
  if constexpr (PF) stage_half(gA + 128 * DIMK + ko, DIMK, An + 128 * 64, wv, lane);
  asm volatile("s_waitcnt lgkmcnt(0)" ::: "memory");
  __builtin_amdgcn_sched_barrier(0);
  __builtin_amdgcn_s_setprio(1);
#pragma unroll
  for (int m = 0; m < 4; ++m)
#pragma unroll
    for (int n = 0; n < 2; ++n) {
      accG[m + 4][n] = __builtin_amdgcn_mfma_f32_16x16x32_bf16(a[m][0], b1[n][0], accG[m + 4][n], 0, 0, 0);
      accU[m + 4][n] = __builtin_amdgcn_mfma_f32_16x16x32_bf16(a[m][0], b3[n][0], accU[m + 4][n], 0, 0, 0);
    }
  __builtin_amdgcn_s_setprio(0);
  // ---- ph3: read A-high ks1; MFMA high-ks1
#pragma unroll
  for (int m = 0; m < 4; ++m)
    a[m][1] = ldsf(Ac, (m + 4) * 32 + wr * 16 + lrow, 4 + grp);
  asm volatile("s_waitcnt lgkmcnt(0)" ::: "memory");
  __builtin_amdgcn_sched_barrier(0);
  __builtin_amdgcn_s_setprio(1);
#pragma unroll
  for (int m = 0; m < 4; ++m)
#pragma unroll
    for (int n = 0; n < 2; ++n) {
      accG[m + 4][n] = __builtin_amdgcn_mfma_f32_16x16x32_bf16(a[m][1], b1[n][1], accG[m + 4][n], 0, 0, 0);
      accU[m + 4][n] = __builtin_amdgcn_mfma_f32_16x16x32_bf16(a[m][1], b3[n][1], accU[m + 4][n], 0, 0, 0);
    }
  __builtin_amdgcn_s_setprio(0);
}

__global__ __launch_bounds__(512, 2) void gemm1_kernel(
    const uint16_t* __restrict__ xg, const uint16_t* __restrict__ w1b,
    const uint16_t* __restrict__ w3b, uint16_t* __restrict__ hbuf,
    const int* __restrict__ counters) {
  __shared__ __align__(16) uint16_t lsA[2][256 * 64];    // 64 KB
  __shared__ __align__(16) uint16_t lsB1[2][128 * 64];   // 32 KB
  __shared__ __align__(16) uint16_t lsB3[2][128 * 64];   // 32 KB

  const int c0 = counters[0], c1 = counters[1];
  const int t0 = (c0 + 255) >> 8, t1 = (c1 + 255) >> 8;
  // bijective XCD swizzle (m204), rt-major chunks: consecutive same-XCD blocks
  // share the A row-tile (L2-resident) and stream B panels.
  const int NHT = gridDim.y;                       // 22
  const int nwg = gridDim.x * NHT;
  const int orig = blockIdx.y * gridDim.x + blockIdx.x;
  const int q = nwg >> 3, r = nwg & 7;
  const int xcd = orig & 7, loc = orig >> 3;
  const int swz = (xcd < r ? xcd * (q + 1) : r * (q + 1) + (xcd - r) * q) + loc;
  const int rt = swz / NHT;
  const int ht = swz - rt * NHT;
  if (rt >= t0 + t1) return;
  const int mod = (rt < t0) ? 0 : 1;
  const long row0 = (long)rt * 256;

  const int tid = threadIdx.x, lane = tid & 63, wv = tid >> 6;
  const int wr = wv >> 2, wc = wv & 3;            // 2M x 4N waves
  const int lrow = lane & 15, grp = lane >> 4;

  const uint16_t* gA  = xg  + row0 * DIMK;
  const uint16_t* gB1 = w1b + ((long)mod * HID + ht * 128) * DIMK;
  const uint16_t* gB3 = w3b + ((long)mod * HID + ht * 128) * DIMK;

  f32x4 accG[8][2], accU[8][2];
#pragma unroll
  for (int m = 0; m < 8; ++m)
#pragma unroll
    for (int n = 0; n < 2; ++n) {
      accG[m][n] = {0.f, 0.f, 0.f, 0.f};
      accU[m][n] = {0.f, 0.f, 0.f, 0.f};
    }

  // prologue: tile 0 -> buf 0, group1 then group2 (defines vmcnt age order)
  stage_half(gA,              DIMK, &lsA[0][0],        wv, lane);
  stage_half(gB1,             DIMK, &lsB1[0][0],       wv, lane);
  stage_half(gB3,             DIMK, &lsB3[0][0],       wv, lane);
  stage_half(gA + 128 * DIMK, DIMK, &lsA[0][128 * 64], wv, lane);

  const int NT = DIMK / 64;                        // 16
  int cur = 0;
  for (int t = 0; t < NT - 1; ++t) {
    g1_tile<true, 2, 6>(&lsA[cur][0], &lsB1[cur][0], &lsB3[cur][0],
                        &lsA[cur ^ 1][0], &lsB1[cur ^ 1][0], &lsB3[cur ^ 1][0],
                        gA, gB1, gB3, (long)(t + 1) * 64,
                        wv, lane, wr, wc, lrow, grp, accG, accU);
    cur ^= 1;
  }
  g1_tile<false, 2, 0>(&lsA[cur][0], &lsB1[cur][0], &lsB3[cur][0],
                       &lsA[cur ^ 1][0], &lsB1[cur ^ 1][0], &lsB3[cur ^ 1][0],
                       gA, gB1, gB3, 0,
                       wv, lane, wr, wc, lrow, grp, accG, accU);

  // epilogue: h = silu(x1) * x3 -> bf16 (gap rows harmless, never scattered)
#pragma unroll
  for (int m = 0; m < 8; ++m)
#pragma unroll
    for (int n = 0; n < 2; ++n) {
      const int col = ht * 128 + wc * 32 + n * 16 + lrow;
#pragma unroll
      for (int i = 0; i < 4; ++i) {
        const long row = row0 + m * 32 + wr * 16 + grp * 4 + i;
        float g = accG[m][n][i];
        float u = accU[m][n][i];
        float hv = (g / (1.f + __expf(-g))) * u;
        hbuf[row * HID + col] = f2bf(hv);
      }
    }
}

// ---------------- GEMM2: 256x256 tile, 4 phases/K-tile ----------------
// Stage groups: group1 = {A-low, B-low, B-high} (6 loads), group2 = {A-high} (2).
// Same wait pattern as gemm1: vmcnt(2) @ph0, vmcnt(6) @ph2.

template<bool PF, int W0, int W2>
__device__ __forceinline__ void g2_tile(
    const uint16_t* Ac, const uint16_t* Bc, uint16_t* An, uint16_t* Bn,
    const uint16_t* gA, const uint16_t* gB, long ko,
    int wv, int lane, int wr, int wc, int lrow, int grp,
    f32x4 (&acc)[8][4]) {
  bf16x8 a[4][2], b[4][2];
  // ---- ph0: guard group1; read ks0 of A-low + own B-half; stage group1(t+1)
  wait_vm<W0>();
  __builtin_amdgcn_s_barrier();
  asm volatile("" ::: "memory");
#pragma unroll
  for (int m = 0; m < 4; ++m)
    a[m][0] = ldsf(Ac, m * 32 + wr * 16 + lrow, grp);
#pragma unroll
  for (int n = 0; n < 4; ++n)
    b[n][0] = ldsf(Bc, wc * 64 + n * 16 + lrow, grp);
  if constexpr (PF) {
    stage_half(gA + ko,             HID, An,            wv, lane);
    stage_half(gB + ko,             HID, Bn,            wv, lane);
    stage_half(gB + 128 * HID + ko, HID, Bn + 128 * 64, wv, lane);
  }
  asm volatile("s_waitcnt lgkmcnt(0)" ::: "memory");
  __builtin_amdgcn_sched_barrier(0);
  __builtin_amdgcn_s_setprio(1);
#pragma unroll
  for (int m = 0; m < 4; ++m)
#pragma unroll
    for (int n = 0; n < 4; ++n)
      acc[m][n] = __builtin_amdgcn_mfma_f32_16x16x32_bf16(a[m][0], b[n][0], acc[m][n], 0, 0, 0);
  __builtin_amdgcn_s_setprio(0);
  // ---- ph1: ks1 of A-low + B
#pragma unroll
  for (int m = 0; m < 4; ++m)
    a[m][1] = ldsf(Ac, m * 32 + wr * 16 + lrow, 4 + grp);
#pragma unroll
  for (int n = 0; n < 4; ++n)
    b[n][1] = ldsf(Bc, wc * 64 + n * 16 + lrow, 4 + grp);
  asm volatile("s_waitcnt lgkmcnt(0)" ::: "memory");
  __builtin_amdgcn_sched_barrier(0);
  __builtin_amdgcn_s_setprio(1);
#pragma unroll
  for (int m = 0; m < 4; ++m)
#pragma unroll
    for (int n = 0; n < 4; ++n)
      acc[m][n] = __builtin_amdgcn_mfma_f32_16x16x32_bf16(a[m][1], b[n][1], acc[m][n], 0, 0, 0);
  __builtin_amdgcn_s_setprio(0);
  // ---- ph2: guard group2; A-high ks0; stage group2(t+1)
  wait_vm<W2>();
  __builtin_amdgcn_s_barrier();
  asm volatile("" ::: "memory");
#pragma unroll
  for (int m = 0; m < 4; ++m)
    a[m][0] = ldsf(Ac, (m + 4) * 32 + wr * 16 + lrow, grp);
  if constexpr (PF) stage_half(gA + 128 * HID + ko, HID, An + 128 * 64, wv, lane);
  asm volatile("s_waitcnt lgkmcnt(0)" ::: "memory");
  __builtin_amdgcn_sched_barrier(0);
  __builtin_amdgcn_s_setprio(1);
#pragma unroll
  for (int m = 0; m < 4; ++m)
#pragma unroll
    for (int n = 0; n < 4; ++n)
      acc[m + 4][n] = __builtin_amdgcn_mfma_f32_16x16x32_bf16(a[m][0], b[n][0], acc[m + 4][n], 0, 0, 0);
  __builtin_amdgcn_s_setprio(0);
  // ---- ph3: A-high ks1
#pragma unroll
  for (int m = 0; m < 4; ++m)
    a[m][1] = ldsf(Ac, (m + 4) * 32 + wr * 16 + lrow, 4 + grp);
  asm volatile("s_waitcnt lgkmcnt(0)" ::: "memory");
  __builtin_amdgcn_sched_barrier(0);
  __builtin_amdgcn_s_setprio(1);
#pragma unroll
  for (int m = 0; m < 4; ++m)
#pragma unroll
    for (int n = 0; n < 4; ++n)
      acc[m + 4][n] = __builtin_amdgcn_mfma_f32_16x16x32_bf16(a[m][1], b[n][1], acc[m + 4][n], 0, 0, 0);
  __builtin_amdgcn_s_setprio(0);
}

__global__ __launch_bounds__(512, 2) void gemm2_kernel(
    const uint16_t* __restrict__ hbuf, const uint16_t* __restrict__ w2b,
    const int* __restrict__ counters, const int* __restrict__ tok,
    float* __restrict__ out) {
  __shared__ __align__(16) uint16_t lsA[2][256 * 64];    // 64 KB
  __shared__ __align__(16) uint16_t lsB[2][256 * 64];    // 64 KB

  const int c0 = counters[0], c1 = counters[1];
  const int t0 = (c0 + 255) >> 8, t1 = (c1 + 255) >> 8;
  const int NCT = gridDim.y;                       // 4
  const int nwg = gridDim.x * NCT;
  const int orig = blockIdx.y * gridDim.x + blockIdx.x;
  const int q = nwg >> 3, r = nwg & 7;
  const int xcd = orig & 7, loc = orig >> 3;
  const int swz = (xcd < r ? xcd * (q + 1) : r * (q + 1) + (xcd - r) * q) + loc;
  const int rt = swz / NCT;
  const int ct = swz - rt * NCT;
  if (rt >= t0 + t1) return;
  const int mod = (rt < t0) ? 0 : 1;
  const long row0 = (long)rt * 256;
  const int vlimit = (mod == 0) ? c0 : t0 * 256 + c1;

  const int tid = threadIdx.x, lane = tid & 63, wv = tid >> 6;
  const int wr = wv >> 2, wc = wv & 3;
  const int lrow = lane & 15, grp = lane >> 4;

  const uint16_t* gA = hbuf + row0 * HID;
  const uint16_t* gB = w2b + ((long)mod * DIMK + ct * 256) * HID;

  f32x4 acc[8][4];
#pragma unroll
  for (int m = 0; m < 8; ++m)
#pragma unroll
    for (int n = 0; n < 4; ++n) acc[m][n] = {0.f, 0.f, 0.f, 0.f};

  // prologue: group1 then group2
  stage_half(gA,             HID, &lsA[0][0],        wv, lane);
  stage_half(gB,             HID, &lsB[0][0],        wv, lane);
  stage_half(gB + 128 * HID, HID, &lsB[0][128 * 64], wv, lane);
  stage_half(gA + 128 * HID, HID, &lsA[0][128 * 64], wv, lane);

  const int NT = HID / 64;                         // 44
  int cur = 0;
  for (int t = 0; t < NT - 1; ++t) {
    g2_tile<true, 2, 6>(&lsA[cur][0], &lsB[cur][0],
                        &lsA[cur ^ 1][0], &lsB[cur ^ 1][0],
                        gA, gB, (long)(t + 1) * 64,
                        wv, lane, wr, wc, lrow, grp, acc);
    cur ^= 1;
  }
  g2_tile<false, 2, 0>(&lsA[cur][0], &lsB[cur][0],
                       &lsA[cur ^ 1][0], &lsB[cur ^ 1][0],
                       gA, gB, 0,
                       wv, lane, wr, wc, lrow, grp, acc);

#pragma unroll
  for (int m = 0; m < 8; ++m)
#pragma unroll
    for (int n = 0; n < 4; ++n) {
      const int col = ct * 256 + wc * 64 + n * 16 + lrow;
#pragma unroll
      for (int i = 0; i < 4; ++i) {
        const int row = (int)row0 + m * 32 + wr * 16 + grp * 4 + i;
        if (row < vlimit) {
          out[(long)tok[row] * DIMK + col] = acc[m][n][i];
        }
      }
    }
}

extern "C" void kernel_launch(void* const* d_in, const int* in_sizes, int n_in,
                              void* d_out, int out_size, void* d_ws, size_t ws_size,
                              hipStream_t stream) {
  const float* x    = (const float*)d_in[0];
  const int*   mids = (const int*)d_in[1];
  const float* W1   = (const float*)d_in[2];
  const float* W2   = (const float*)d_in[3];
  const float* W3   = (const float*)d_in[4];
  float* out = (float*)d_out;

  const int T   = in_sizes[1];                       // 32768 tokens
  const int NB  = (T + 255) / 256;                   // 128 count blocks
  const int CAP = ((T + 255) & ~255) + 256;          // 256-aligned capacity + gap tile

  char* ws = (char*)d_ws;
  int* counters = (int*)ws;                          // [c0, c1]
  int* bc   = (int*)(ws + 256);                      // per-block counts [NB][2]
  int* base = (int*)(ws + 256 + 2048);               // per-block bases  [NB][2]
  int* tok  = (int*)(ws + 256 + 4096);               // slot -> token
  int* slotof = tok + ((CAP + 63) & ~63);            // token -> slot
  size_t off = 256 + 4096 + (size_t)((CAP + 63) & ~63) * 4 + (size_t)((T + 63) & ~63) * 4;
  off = (off + 255) & ~(size_t)255;
  uint16_t* xg  = (uint16_t*)(ws + off); off += (size_t)CAP * DIMK * 2;
  uint16_t* w1b = (uint16_t*)(ws + off); off += (size_t)2 * HID * DIMK * 2;
  uint16_t* w3b = (uint16_t*)(ws + off); off += (size_t)2 * HID * DIMK * 2;
  uint16_t* w2b = (uint16_t*)(ws + off); off += (size_t)2 * DIMK * HID * 2;
  uint16_t* hbuf = (uint16_t*)(ws + off); off += (size_t)CAP * HID * 2;
  (void)ws_size; (void)n_in; (void)out_size;

  count_kernel<<<NB, 256, 0, stream>>>(mids, bc, T);
  scan_kernel<<<1, 256, 0, stream>>>(bc, base, counters, NB);
  slot_kernel<<<NB, 256, 0, stream>>>(mids, base, counters, tok, slotof, T);
  copy_kernel<<<(T + 3) / 4, 256, 0, stream>>>(x, slotof, xg, T);

  const long NW = (long)2 * HID * DIMK;              // elements per weight tensor
  const int cblk = (int)((NW / 4 + 255) / 256);
  convert_kernel<<<cblk, 256, 0, stream>>>(W1, w1b, NW);
  convert_kernel<<<cblk, 256, 0, stream>>>(W3, w3b, NW);
  convert_kernel<<<cblk, 256, 0, stream>>>(W2, w2b, NW);

  const int rtiles = CAP / 256;                      // 129
  gemm1_kernel<<<dim3(rtiles, HID / 128), 512, 0, stream>>>(xg, w1b, w3b, hbuf, counters);
  gemm2_kernel<<<dim3(rtiles, DIMK / 256), 512, 0, stream>>>(hbuf, w2b, counters, tok, out);
}